// Round 4
// baseline (144.988 us; speedup 1.0000x reference)
//
#include <hip/hip_runtime.h>
#include <hip/hip_bf16.h>

// PointConv: N=32768 points, E=786432 edges (sorted by out_index), K<=64
// product[n][c][m] = inv_n * sum_edges x_in[src][c] * celu(celu(pos_local@W1)@W2)[m]
// out[n][k] = product[n].flat(1024) @ W3[1024][64] + b3[k]
//
// R15: R13 fused structure (256-thr, 4 waves, 8 pts/block) + COUNT-SORTED
// point assignment. Points are bucketed by step count (cnt<=32 -> 1 step,
// else 2) via a tiny sort kernel; agg processes perm[w*2+i]. ~97% of blocks
// get uniform wave workloads -> epilogue barrier straggler wait eliminated.
// Dead next-batch prefetch elided via wave-uniform `more` (all ns=2 waves).

typedef __attribute__((ext_vector_type(8))) short short8;
typedef __attribute__((ext_vector_type(4))) float f32x4;
typedef __attribute__((ext_vector_type(2))) unsigned int u32x2;
typedef __attribute__((ext_vector_type(4))) unsigned int u32x4;
typedef __fp16 f16x2 __attribute__((ext_vector_type(2)));
typedef __fp16 f16x8 __attribute__((ext_vector_type(8)));

static __device__ __forceinline__ int rfl(int v){
    return __builtin_amdgcn_readfirstlane(v);
}
static __device__ __forceinline__ float celu1(float x){
    return x > 0.0f ? x : (__expf(x) - 1.0f);
}
static __device__ __forceinline__ unsigned int pkh(float lo, float hi){
    f16x2 t = __builtin_amdgcn_cvt_pkrtz(lo, hi);
    return __builtin_bit_cast(unsigned int, t);
}
// round-to-nearest-even f16 pack (matches previous (__fp16) casts of P)
static __device__ __forceinline__ unsigned int pkh_rte(float lo, float hi){
    unsigned short a = __builtin_bit_cast(unsigned short, (__fp16)lo);
    unsigned short b = __builtin_bit_cast(unsigned short, (__fp16)hi);
    return (unsigned int)a | ((unsigned int)b << 16);
}

// ---------------- Kernel 0: seg boundaries + W3/W2 prep (merged) -------------
// W3frag is fragment-ordered for n-tile t, K-chunk kk with the PERMUTED k':
//   k' = q*256 + r*16 + mt*4 + i   <->   k = (q*4+i)*64 + mt*16 + r
// so the agg epilogue's A-side (flush-register order) and B-side agree.
__global__ void setup_kernel(const int* __restrict__ out_index,
                             int* __restrict__ seg_start, int E, int N,
                             const float* __restrict__ W3, const float* __restrict__ W2,
                             __fp16* __restrict__ W3frag,
                             unsigned int* __restrict__ W2f16,
                             int* __restrict__ cnts)
{
    int o = blockIdx.x * blockDim.x + threadIdx.x;
    if (o == 0) { cnts[0] = 0; cnts[1] = 0; }
    if (o < E) {
        int cur = out_index[o];
        if (o == 0) {
            for (int v = 0; v <= cur; ++v) seg_start[v] = 0;
        } else {
            int prev = out_index[o - 1];
            for (int v = prev + 1; v <= cur; ++v) seg_start[v] = o;
        }
        if (o == E - 1) {
            for (int v = cur + 1; v <= N; ++v) seg_start[v] = E;
        }
    }
    if (o < 65536) {
        int j    = o & 7;
        int lane = (o >> 3) & 63;
        int t    = (o >> 9) & 3;
        int kk   = o >> 11;
        int kp = kk * 32 + (lane >> 4) * 8 + j;      // permuted k'
        int qq = kp >> 8;
        int rr = (kp >> 4) & 15;
        int mt = (kp >> 2) & 3;
        int ii = kp & 3;
        int k = (qq * 4 + ii) * 64 + mt * 16 + rr;   // true flat k = c*64 + m
        int n = t * 16 + (lane & 15);
        W3frag[o] = (__fp16)W3[k * 64 + n];
    } else if (o < 65536 + 1024) {
        int o2 = o - 65536;
        int nt   = o2 >> 8;
        int lane = (o2 >> 2) & 63;
        int d    = o2 & 3;
        int q = lane >> 4, rr = lane & 15;
        unsigned int v = 0;
        if (q < 2) {
            int k0 = q * 8 + 2 * d;
            int n = nt * 16 + rr;
            v = pkh(W2[k0 * 64 + n], W2[(k0 + 1) * 64 + n]);
        }
        W2f16[o2] = v;
    }
}

// ---------------- Kernel 0b: bucket points by step count ---------------------
// cnt<=32 (1 K-step) -> slots from the front; cnt>32 (2 K-steps) -> from the
// back. Within a bucket order is arbitrary (atomics); output is by point id,
// so results are deterministic regardless.
__global__ void sort_kernel(const int* __restrict__ seg_start,
                            int* __restrict__ perm, int* __restrict__ cnts, int N)
{
    int v = blockIdx.x * blockDim.x + threadIdx.x;
    if (v < N) {
        int cnt = seg_start[v + 1] - seg_start[v];
        int pos;
        if (cnt <= 32) pos = atomicAdd(&cnts[0], 1);
        else           pos = N - 1 - atomicAdd(&cnts[1], 1);
        perm[pos] = v;
    }
}

// ---------------- Kernel 1: edge aggregation + fused output GEMM -------------
// Wave wv (0..3) owns points perm[2w], perm[2w+1], w = blockIdx*4+wv.
__global__ __launch_bounds__(256) void agg_kernel(
    const float* __restrict__ x_in, const float* __restrict__ pos_in,
    const float* __restrict__ pos_out, const int* __restrict__ in_index,
    const int* __restrict__ seg_start, const int* __restrict__ perm,
    const float* __restrict__ W1,
    const unsigned int* __restrict__ W2f16, const __fp16* __restrict__ W3frag,
    const float* __restrict__ b3, float* __restrict__ out, int E)
{
    __shared__ __align__(16) unsigned char ldsraw[4 * 9216];
    int lane = threadIdx.x & 63;
    int wv = threadIdx.x >> 6;
    unsigned char* H2L = ldsraw + wv * 9216;   // staging 0..3071; tile rows m*144
    int w = blockIdx.x * 4 + wv;

    int r = lane & 15;
    int q = lane >> 4;
    int l31 = lane & 31;
    bool hihalf = lane >= 32;
    int vq = 32 * q;                           // byte-addr component for bpermute

    // zero block for padded-K A-frag lanes (bytes 9200..9215 never written)
    if (lane == 0) *(u32x4*)(H2L + 9200) = (u32x4){0u, 0u, 0u, 0u};

    // W2 B-frags (constant)
    f16x8 bfr[4];
    #pragma unroll
    for (int nt = 0; nt < 4; ++nt)
        bfr[nt] = __builtin_bit_cast(f16x8, *((const u32x4*)W2f16 + nt * 64 + lane));

    // W1 columns (uniform -> SGPRs)
    float w1a[16], w1b[16], w1c[16];
    #pragma unroll
    for (int c = 0; c < 16; ++c) { w1a[c] = W1[c]; w1b[c] = W1[16 + c]; w1c[c] = W1[32 + c]; }

    // per-wave point table (2 permuted points, wave-uniform)
    int pid[2], sg[2], cf[2], cc[2], p[3];
    pid[0] = rfl(perm[w * 2]);
    pid[1] = rfl(perm[w * 2 + 1]);
    p[0] = 0;
    #pragma unroll
    for (int i = 0; i < 2; ++i) {
        sg[i] = rfl(seg_start[pid[i]]);
        int se = rfl(seg_start[pid[i] + 1]);
        cf[i] = se - sg[i];
        cc[i] = cf[i] > 64 ? 64 : cf[i];
        p[i + 1] = p[i] + (cc[i] > 32 ? 2 : 1);
    }
    int ns = p[2];                             // total 32-slot steps, 2..4

    // descriptor for step t (wave-uniform; t >= ns yields rem<=0 -> all-pad)
    #define STEP_DESC(t, nS, cfS, remS, ebS)                         \
        {                                                            \
            int i_ = 0, pi_ = 0;                                     \
            if ((t) >= p[1]) { i_ = 1; pi_ = p[1]; }                 \
            int cf_ = cf[0], cc_ = cc[0], sg_ = sg[0], id_ = pid[0]; \
            if (i_ >= 1) { cf_ = cf[1]; cc_ = cc[1]; sg_ = sg[1]; id_ = pid[1]; } \
            int kb_ = ((t) - pi_) * 32;                              \
            (nS) = id_; (cfS) = cf_;                                 \
            (remS) = cc_ - kb_; (ebS) = sg_ + kb_;                   \
        }

    f32x4 C[4];
    #pragma unroll
    for (int mt = 0; mt < 4; ++mt) C[mt] = (f32x4){0.f, 0.f, 0.f, 0.f};
    int cur_n = pid[0];
    int cur_cf = cf[0];

    // packed f16 products for the wave's 2 points (static reg arrays).
    // Mid-loop flush is always point slot 0; final flush always slot 1.
    unsigned int pkP0[8], pkP1[8];
    #pragma unroll
    for (int i = 0; i < 8; ++i) { pkP0[i] = 0u; pkP1[i] = 0u; }

    // ---- prologue: batch 0 descriptors + idx + pos prefetch ----
    int nA, cfA, remA, ebA, nB, cfB, remB, ebB;
    STEP_DESC(0, nA, cfA, remA, ebA)
    STEP_DESC(1, nB, cfB, remB, ebB)
    int nH = hihalf ? nB : nA;
    int ebH = hihalf ? ebB : ebA;
    int idx0 = ebH + l31; idx0 = idx0 < E ? idx0 : E - 1;
    int idxs = in_index[idx0];                 // lane l -> src of slot l
    float pox = pos_out[nH * 3 + 0];
    float poy = pos_out[nH * 3 + 1];
    float poz = pos_out[nH * 3 + 2];
    float pi0 = pos_in[idxs * 3 + 0];
    float pi1 = pos_in[idxs * 3 + 1];
    float pi2 = pos_in[idxs * 3 + 2];

    #pragma unroll 1
    for (int b = 0; b < 2; ++b) {
        if (2 * b >= ns) break;
        bool more = (2 * b + 2) < ns;          // wave-uniform

        // ---- prefetch next batch: descriptors + idx vector (only if real) --
        int nA2 = 0, cfA2 = 0, remA2 = 0, ebA2 = 0;
        int nB2 = 0, cfB2 = 0, remB2 = 0, ebB2 = 0;
        int idxs_next = 0;
        float pox2 = 0.f, poy2 = 0.f, poz2 = 0.f;
        if (more) {
            STEP_DESC(2 * b + 2, nA2, cfA2, remA2, ebA2)
            STEP_DESC(2 * b + 3, nB2, cfB2, remB2, ebB2)
            int nH2 = hihalf ? nB2 : nA2;
            int ebH2 = hihalf ? ebB2 : ebA2;
            int idx2 = ebH2 + l31; idx2 = idx2 < E ? idx2 : E - 1;
            idxs_next = in_index[idx2];
            pox2 = pos_out[nH2 * 3 + 0];
            poy2 = pos_out[nH2 * 3 + 1];
            poz2 = pos_out[nH2 * 3 + 2];
        }

        // ---- x A-frags: src via bpermute of idxs (loaded last iter) ----
        f16x8 ax[2];
        #pragma unroll
        for (int h = 0; h < 2; ++h) {
            int remS = h ? remB : remA;
            float xv[8];
            #pragma unroll
            for (int jj = 0; jj < 8; ++jj) {
                // slot = 32h + 8q + jj; bpermute byte addr = 4*slot
                int s = __builtin_amdgcn_ds_bpermute(128 * h + vq + 4 * jj, idxs);
                float x = x_in[s * 16 + r];
                xv[jj] = ((8 * q + jj) < remS) ? x : 0.0f;
            }
            u32x4 t;
            #pragma unroll
            for (int d = 0; d < 4; ++d) t[d] = pkh(xv[2 * d], xv[2 * d + 1]);
            ax[h] = __builtin_bit_cast(f16x8, t);
        }

        // ---- h1 (lane = slot): pos already prefetched ----
        float d0 = pi0 - pox;
        float d1 = pi1 - poy;
        float d2 = pi2 - poz;
        unsigned int hp[8];
        #pragma unroll
        for (int cp = 0; cp < 8; ++cp) {
            float a0 = celu1(fmaf(d0, w1a[2 * cp],     fmaf(d1, w1b[2 * cp],     d2 * w1c[2 * cp])));
            float a1 = celu1(fmaf(d0, w1a[2 * cp + 1], fmaf(d1, w1b[2 * cp + 1], d2 * w1c[2 * cp + 1])));
            hp[cp] = pkh(a0, a1);
        }
        *(u32x4*)(H2L + lane * 48)      = (u32x4){hp[0], hp[1], hp[2], hp[3]};
        *(u32x4*)(H2L + lane * 48 + 16) = (u32x4){hp[4], hp[5], hp[6], hp[7]};
        f16x8 af[4];
        #pragma unroll
        for (int et = 0; et < 4; ++et) {
            int abase = (q < 2) ? ((et * 16 + r) * 48 + q * 16) : 9200;
            af[et] = __builtin_bit_cast(f16x8, *(const u32x4*)(H2L + abase));
        }

        // ---- h2 = celu(h1 @ W2) via MFMA; tile write H2L[m][slot] ----
        #pragma unroll
        for (int pp = 0; pp < 2; ++pp) {
            f32x4 D[4][2];
            #pragma unroll
            for (int et = 0; et < 4; ++et)
                #pragma unroll
                for (int j = 0; j < 2; ++j)
                    D[et][j] = __builtin_amdgcn_mfma_f32_16x16x32_f16(
                        af[et], bfr[2 * pp + j], (f32x4){0.f, 0.f, 0.f, 0.f}, 0, 0, 0);
            #pragma unroll
            for (int et = 0; et < 4; ++et)
                #pragma unroll
                for (int j = 0; j < 2; ++j) {
                    int nt = 2 * pp + j;
                    float v0 = celu1(D[et][j][0]);
                    float v1 = celu1(D[et][j][1]);
                    float v2 = celu1(D[et][j][2]);
                    float v3 = celu1(D[et][j][3]);
                    *(u32x2*)(H2L + (nt * 16 + r) * 144 + et * 32 + q * 8) =
                        (u32x2){pkh(v0, v1), pkh(v2, v3)};
                }
        }

        // ---- pos prefetch for next batch (idxs_next has landed by now) ----
        float pi0n = 0.f, pi1n = 0.f, pi2n = 0.f;
        if (more) {
            pi0n = pos_in[idxs_next * 3 + 0];
            pi1n = pos_in[idxs_next * 3 + 1];
            pi2n = pos_in[idxs_next * 3 + 2];
        }

        // ---- P accumulation per half, flush to registers on transitions ----
        #pragma unroll
        for (int h = 0; h < 2; ++h) {
            int nS  = h ? nB : nA;
            int cfS = h ? cfB : cfA;
            if (rfl(nS) != cur_n) {
                float inv = cur_cf > 0 ? 1.0f / (float)cur_cf : 0.0f;
                #pragma unroll
                for (int mt = 0; mt < 4; ++mt) {
                    pkP0[2 * mt]     = pkh_rte(C[mt][0] * inv, C[mt][1] * inv);
                    pkP0[2 * mt + 1] = pkh_rte(C[mt][2] * inv, C[mt][3] * inv);
                }
                #pragma unroll
                for (int mt = 0; mt < 4; ++mt) C[mt] = (f32x4){0.f, 0.f, 0.f, 0.f};
                cur_n = nS; cur_cf = cfS;
            }
            #pragma unroll
            for (int mt = 0; mt < 4; ++mt) {
                f16x8 bb = __builtin_bit_cast(f16x8,
                    *(u32x4*)(H2L + (mt * 16 + r) * 144 + h * 64 + q * 16));
                C[mt] = __builtin_amdgcn_mfma_f32_16x16x32_f16(ax[h], bb, C[mt], 0, 0, 0);
            }
        }

        // ---- rotate pipeline registers ----
        if (more) {
            nA = nA2; cfA = cfA2; remA = remA2; ebA = ebA2;
            nB = nB2; cfB = cfB2; remB = remB2; ebB = ebB2;
            idxs = idxs_next;
            pox = pox2; poy = poy2; poz = poz2;
            pi0 = pi0n; pi1 = pi1n; pi2 = pi2n;
        }
    }

    // final flush (always the wave's second point -> slot 1)
    {
        float inv = cur_cf > 0 ? 1.0f / (float)cur_cf : 0.0f;
        #pragma unroll
        for (int mt = 0; mt < 4; ++mt) {
            pkP1[2 * mt]     = pkh_rte(C[mt][0] * inv, C[mt][1] * inv);
            pkP1[2 * mt + 1] = pkh_rte(C[mt][2] * inv, C[mt][3] * inv);
        }
    }
    #undef STEP_DESC

    // ================= fused output GEMM =================
    // P_lds layout: row = local point (0..7), 1024 f16 in k' order, 2048B/row,
    // 16B chunks XOR-swizzled by ((row&7)<<4). Rows 8..15 of the A-frag read a
    // zeroed broadcast slot at byte 16384.
    __syncthreads();   // all waves done with H2L staging
    {
        int row0 = wv * 2;
        unsigned int base0 = (unsigned int)(row0 * 2048 + q * 512 + r * 32);
        unsigned int base1 = base0 + 2048u;
        unsigned int swz0 = (unsigned int)((row0 & 7) << 4);
        unsigned int swz1 = (unsigned int)(((row0 + 1) & 7) << 4);
        *(u32x4*)(ldsraw + ((base0)       ^ swz0)) = (u32x4){pkP0[0], pkP0[1], pkP0[2], pkP0[3]};
        *(u32x4*)(ldsraw + ((base0 + 16u) ^ swz0)) = (u32x4){pkP0[4], pkP0[5], pkP0[6], pkP0[7]};
        *(u32x4*)(ldsraw + ((base1)       ^ swz1)) = (u32x4){pkP1[0], pkP1[1], pkP1[2], pkP1[3]};
        *(u32x4*)(ldsraw + ((base1 + 16u) ^ swz1)) = (u32x4){pkP1[4], pkP1[5], pkP1[6], pkP1[7]};
        if (threadIdx.x == 0) *(u32x4*)(ldsraw + 16384) = (u32x4){0u, 0u, 0u, 0u};
    }
    __syncthreads();
    {
        // wave wv computes out cols [wv*16, wv*16+16) for the block's 8 points
        const short8* Bp = (const short8*)W3frag + wv * 64 + lane;
        f32x4 Cg = (f32x4){0.f, 0.f, 0.f, 0.f};
        unsigned int abase = (unsigned int)(r * 2048 + q * 16);
        unsigned int aswz  = (unsigned int)((r & 7) << 4);
        bool arow_pad = (r >= 8);
        #pragma unroll 8
        for (int kk = 0; kk < 32; ++kk) {
            unsigned int ad = (abase + (unsigned int)(kk * 64)) ^ aswz;
            if (arow_pad) ad = 16384u;
            f16x8 a  = __builtin_bit_cast(f16x8, *(const u32x4*)(ldsraw + ad));
            f16x8 bf = __builtin_bit_cast(f16x8, Bp[kk * 256]);   // frag (kk*4 + wv)
            Cg = __builtin_amdgcn_mfma_f32_16x16x32_f16(a, bf, Cg, 0, 0, 0);
        }
        if (q < 2) {   // D rows q*4+i in [0,8) are the valid points
            int colbase = wv * 16 + r;
            float bias = b3[colbase];
            #pragma unroll
            for (int i = 0; i < 4; ++i) {
                int prow = perm[blockIdx.x * 8 + q * 4 + i];
                out[(size_t)prow * 64 + colbase] = Cg[i] + bias;
            }
        }
    }
}

extern "C" void kernel_launch(void* const* d_in, const int* in_sizes, int n_in,
                              void* d_out, int out_size, void* d_ws, size_t ws_size,
                              hipStream_t stream)
{
    const float* x_in    = (const float*)d_in[0];
    const float* pos_in  = (const float*)d_in[1];
    const float* pos_out = (const float*)d_in[2];
    const int* in_index  = (const int*)d_in[3];
    const int* out_index = (const int*)d_in[4];
    const float* W1 = (const float*)d_in[5];
    const float* W2 = (const float*)d_in[6];
    const float* W3 = (const float*)d_in[7];
    const float* b3 = (const float*)d_in[8];

    int N = in_sizes[0] / 16;    // 32768
    int E = in_sizes[3];         // 786432
    float* out = (float*)d_out;

    // workspace: seg (N+1) | W3frag (128KB) | W2f16 (4KB) | perm (N) | cnts (2)
    char* ws = (char*)d_ws;
    int* seg = (int*)ws;
    size_t off = (((size_t)(N + 1) * 4 + 255) & ~(size_t)255);
    __fp16* W3frag = (__fp16*)(ws + off);
    off += (size_t)65536 * 2;
    unsigned int* W2f16 = (unsigned int*)(ws + off);
    off += (size_t)1024 * 4;
    int* perm = (int*)(ws + off);
    off += (size_t)N * 4;
    int* cnts = (int*)(ws + off);

    setup_kernel<<<(E + 255) / 256, 256, 0, stream>>>(out_index, seg, E, N,
                                                      W3, W2, W3frag, W2f16, cnts);
    sort_kernel<<<(N + 255) / 256, 256, 0, stream>>>(seg, perm, cnts, N);
    agg_kernel<<<N / 8, 256, 0, stream>>>(x_in, pos_in, pos_out, in_index, seg,
                                          perm, W1, W2f16, W3frag, b3, out, E);
}

// Round 5
// 139.554 us; speedup vs baseline: 1.0389x; 1.0389x over previous
//
#include <hip/hip_runtime.h>
#include <hip/hip_bf16.h>

// PointConv: N=32768 points, E=786432 edges (sorted by out_index), K<=64
// product[n][c][m] = inv_n * sum_edges x_in[src][c] * celu(celu(pos_local@W1)@W2)[m]
// out[n][k] = product[n].flat(1024) @ W3[1024][64] + b3[k]
//
// R16: sorted uniform blocks + 512-thread geometry.
// - sort_kernel: block-aggregated bucketing (ballot/popc + 2 atomics/block,
//   256 total) replacing R15's ~1024 serialized same-address wave atomics.
// - agg: 8 waves x 2 points = 16 pts/block; sorted perm makes all 8 waves
//   uniform in >=97% of blocks so the epilogue barrier has no stragglers.
// - Epilogue: full 16-row M-tile (R14 split-k: wave -> ntile wv&3, k-half
//   wv>>2, LDS partial reduce); W3frag L2 traffic halved vs R15 (256MB).

typedef __attribute__((ext_vector_type(8))) short short8;
typedef __attribute__((ext_vector_type(4))) float f32x4;
typedef __attribute__((ext_vector_type(2))) unsigned int u32x2;
typedef __attribute__((ext_vector_type(4))) unsigned int u32x4;
typedef __fp16 f16x2 __attribute__((ext_vector_type(2)));
typedef __fp16 f16x8 __attribute__((ext_vector_type(8)));

static __device__ __forceinline__ int rfl(int v){
    return __builtin_amdgcn_readfirstlane(v);
}
static __device__ __forceinline__ float celu1(float x){
    return x > 0.0f ? x : (__expf(x) - 1.0f);
}
static __device__ __forceinline__ unsigned int pkh(float lo, float hi){
    f16x2 t = __builtin_amdgcn_cvt_pkrtz(lo, hi);
    return __builtin_bit_cast(unsigned int, t);
}
// round-to-nearest-even f16 pack (matches previous (__fp16) casts of P)
static __device__ __forceinline__ unsigned int pkh_rte(float lo, float hi){
    unsigned short a = __builtin_bit_cast(unsigned short, (__fp16)lo);
    unsigned short b = __builtin_bit_cast(unsigned short, (__fp16)hi);
    return (unsigned int)a | ((unsigned int)b << 16);
}

// ---------------- Kernel 0: seg boundaries + W3/W2 prep (merged) -------------
// W3frag is fragment-ordered for n-tile t, K-chunk kk with the PERMUTED k':
//   k' = q*256 + r*16 + mt*4 + i   <->   k = (q*4+i)*64 + mt*16 + r
// so the agg epilogue's A-side (flush-register order) and B-side agree.
__global__ void setup_kernel(const int* __restrict__ out_index,
                             int* __restrict__ seg_start, int E, int N,
                             const float* __restrict__ W3, const float* __restrict__ W2,
                             __fp16* __restrict__ W3frag,
                             unsigned int* __restrict__ W2f16,
                             int* __restrict__ cnts)
{
    int o = blockIdx.x * blockDim.x + threadIdx.x;
    if (o == 0) { cnts[0] = 0; cnts[1] = 0; }
    if (o < E) {
        int cur = out_index[o];
        if (o == 0) {
            for (int v = 0; v <= cur; ++v) seg_start[v] = 0;
        } else {
            int prev = out_index[o - 1];
            for (int v = prev + 1; v <= cur; ++v) seg_start[v] = o;
        }
        if (o == E - 1) {
            for (int v = cur + 1; v <= N; ++v) seg_start[v] = E;
        }
    }
    if (o < 65536) {
        int j    = o & 7;
        int lane = (o >> 3) & 63;
        int t    = (o >> 9) & 3;
        int kk   = o >> 11;
        int kp = kk * 32 + (lane >> 4) * 8 + j;      // permuted k'
        int qq = kp >> 8;
        int rr = (kp >> 4) & 15;
        int mt = (kp >> 2) & 3;
        int ii = kp & 3;
        int k = (qq * 4 + ii) * 64 + mt * 16 + rr;   // true flat k = c*64 + m
        int n = t * 16 + (lane & 15);
        W3frag[o] = (__fp16)W3[k * 64 + n];
    } else if (o < 65536 + 1024) {
        int o2 = o - 65536;
        int nt   = o2 >> 8;
        int lane = (o2 >> 2) & 63;
        int d    = o2 & 3;
        int q = lane >> 4, rr = lane & 15;
        unsigned int v = 0;
        if (q < 2) {
            int k0 = q * 8 + 2 * d;
            int n = nt * 16 + rr;
            v = pkh(W2[k0 * 64 + n], W2[(k0 + 1) * 64 + n]);
        }
        W2f16[o2] = v;
    }
}

// ---------------- Kernel 0b: bucket points by step count (cheap) -------------
// cnt<=32 (1 K-step) -> slots from the front; cnt>32 -> from the back.
// Block-aggregated: ballot/popc per wave, LDS scan across 4 waves, 2 atomics
// per block. Within-bucket order arbitrary; output indexed by point id.
__global__ __launch_bounds__(256) void sort_kernel(
    const int* __restrict__ seg_start,
    int* __restrict__ perm, int* __restrict__ cnts, int N)
{
    __shared__ int wh[4], wo[4];
    __shared__ int baseH, baseL;
    int v = blockIdx.x * 256 + threadIdx.x;
    int lane = threadIdx.x & 63;
    int wv = threadIdx.x >> 6;
    int cnt = (v < N) ? (seg_start[v + 1] - seg_start[v]) : 0;
    bool heavy = (v < N) && (cnt > 32);
    unsigned long long m = __ballot(heavy);
    int hpref = __popcll(m & ((1ull << lane) - 1ull));   // heavies before me in wave
    int hcnt = __popcll(m);
    if (lane == 0) wh[wv] = hcnt;
    __syncthreads();
    if (threadIdx.x == 0) {
        int t = 0;
        #pragma unroll
        for (int i = 0; i < 4; ++i) { wo[i] = t; t += wh[i]; }
        int nval = N - blockIdx.x * 256; if (nval > 256) nval = 256;
        baseH = atomicAdd(&cnts[1], t);
        baseL = atomicAdd(&cnts[0], nval - t);
    }
    __syncthreads();
    if (v < N) {
        if (heavy) {
            perm[N - 1 - (baseH + wo[wv] + hpref)] = v;
        } else {
            int lightsBeforeWave = wv * 64 - wo[wv];
            perm[baseL + lightsBeforeWave + (lane - hpref)] = v;
        }
    }
}

// ---------------- Kernel 1: edge aggregation + fused output GEMM -------------
// Wave wv (0..7) owns points perm[2w], perm[2w+1], w = blockIdx*8+wv.
__global__ __launch_bounds__(512) void agg_kernel(
    const float* __restrict__ x_in, const float* __restrict__ pos_in,
    const float* __restrict__ pos_out, const int* __restrict__ in_index,
    const int* __restrict__ seg_start, const int* __restrict__ perm,
    const float* __restrict__ W1,
    const unsigned int* __restrict__ W2f16, const __fp16* __restrict__ W3frag,
    const float* __restrict__ b3, float* __restrict__ out, int E)
{
    __shared__ __align__(16) unsigned char ldsraw[8 * 9216];
    int lane = threadIdx.x & 63;
    int wv = threadIdx.x >> 6;                 // 0..7
    unsigned char* H2L = ldsraw + wv * 9216;   // staging 0..3071; tile rows m*144
    int w = blockIdx.x * 8 + wv;

    int r = lane & 15;
    int q = lane >> 4;
    int l31 = lane & 31;
    bool hihalf = lane >= 32;
    int vq = 32 * q;                           // byte-addr component for bpermute

    // zero block for padded-K A-frag lanes (bytes 9200..9215 never written)
    if (lane == 0) *(u32x4*)(H2L + 9200) = (u32x4){0u, 0u, 0u, 0u};

    // W2 B-frags (constant)
    f16x8 bfr[4];
    #pragma unroll
    for (int nt = 0; nt < 4; ++nt)
        bfr[nt] = __builtin_bit_cast(f16x8, *((const u32x4*)W2f16 + nt * 64 + lane));

    // W1 columns (uniform -> SGPRs)
    float w1a[16], w1b[16], w1c[16];
    #pragma unroll
    for (int c = 0; c < 16; ++c) { w1a[c] = W1[c]; w1b[c] = W1[16 + c]; w1c[c] = W1[32 + c]; }

    // per-wave point table (2 permuted points, wave-uniform)
    int pid[2], sg[2], cf[2], cc[2], p[3];
    pid[0] = rfl(perm[w * 2]);
    pid[1] = rfl(perm[w * 2 + 1]);
    p[0] = 0;
    #pragma unroll
    for (int i = 0; i < 2; ++i) {
        sg[i] = rfl(seg_start[pid[i]]);
        int se = rfl(seg_start[pid[i] + 1]);
        cf[i] = se - sg[i];
        cc[i] = cf[i] > 64 ? 64 : cf[i];
        p[i + 1] = p[i] + (cc[i] > 32 ? 2 : 1);
    }
    int ns = p[2];                             // total 32-slot steps, 2..4

    // descriptor for step t (wave-uniform; t >= ns yields rem<=0 -> all-pad)
    #define STEP_DESC(t, nS, cfS, remS, ebS)                         \
        {                                                            \
            int i_ = 0, pi_ = 0;                                     \
            if ((t) >= p[1]) { i_ = 1; pi_ = p[1]; }                 \
            int cf_ = cf[0], cc_ = cc[0], sg_ = sg[0], id_ = pid[0]; \
            if (i_ >= 1) { cf_ = cf[1]; cc_ = cc[1]; sg_ = sg[1]; id_ = pid[1]; } \
            int kb_ = ((t) - pi_) * 32;                              \
            (nS) = id_; (cfS) = cf_;                                 \
            (remS) = cc_ - kb_; (ebS) = sg_ + kb_;                   \
        }

    f32x4 C[4];
    #pragma unroll
    for (int mt = 0; mt < 4; ++mt) C[mt] = (f32x4){0.f, 0.f, 0.f, 0.f};
    int cur_n = pid[0];
    int cur_cf = cf[0];

    // packed f16 products for the wave's 2 points (static reg arrays).
    // Mid-loop flush is always point slot 0; final flush always slot 1.
    unsigned int pkP0[8], pkP1[8];
    #pragma unroll
    for (int i = 0; i < 8; ++i) { pkP0[i] = 0u; pkP1[i] = 0u; }

    // ---- prologue: batch 0 descriptors + idx + pos prefetch ----
    int nA, cfA, remA, ebA, nB, cfB, remB, ebB;
    STEP_DESC(0, nA, cfA, remA, ebA)
    STEP_DESC(1, nB, cfB, remB, ebB)
    int nH = hihalf ? nB : nA;
    int ebH = hihalf ? ebB : ebA;
    int idx0 = ebH + l31; idx0 = idx0 < E ? idx0 : E - 1;
    int idxs = in_index[idx0];                 // lane l -> src of slot l
    float pox = pos_out[nH * 3 + 0];
    float poy = pos_out[nH * 3 + 1];
    float poz = pos_out[nH * 3 + 2];
    float pi0 = pos_in[idxs * 3 + 0];
    float pi1 = pos_in[idxs * 3 + 1];
    float pi2 = pos_in[idxs * 3 + 2];

    #pragma unroll 1
    for (int b = 0; b < 2; ++b) {
        if (2 * b >= ns) break;
        bool more = (2 * b + 2) < ns;          // wave-uniform

        // ---- prefetch next batch: descriptors + idx vector (only if real) --
        int nA2 = 0, cfA2 = 0, remA2 = 0, ebA2 = 0;
        int nB2 = 0, cfB2 = 0, remB2 = 0, ebB2 = 0;
        int idxs_next = 0;
        float pox2 = 0.f, poy2 = 0.f, poz2 = 0.f;
        if (more) {
            STEP_DESC(2 * b + 2, nA2, cfA2, remA2, ebA2)
            STEP_DESC(2 * b + 3, nB2, cfB2, remB2, ebB2)
            int nH2 = hihalf ? nB2 : nA2;
            int ebH2 = hihalf ? ebB2 : ebA2;
            int idx2 = ebH2 + l31; idx2 = idx2 < E ? idx2 : E - 1;
            idxs_next = in_index[idx2];
            pox2 = pos_out[nH2 * 3 + 0];
            poy2 = pos_out[nH2 * 3 + 1];
            poz2 = pos_out[nH2 * 3 + 2];
        }

        // ---- x A-frags: src via bpermute of idxs (loaded last iter) ----
        f16x8 ax[2];
        #pragma unroll
        for (int h = 0; h < 2; ++h) {
            int remS = h ? remB : remA;
            float xv[8];
            #pragma unroll
            for (int jj = 0; jj < 8; ++jj) {
                // slot = 32h + 8q + jj; bpermute byte addr = 4*slot
                int s = __builtin_amdgcn_ds_bpermute(128 * h + vq + 4 * jj, idxs);
                float x = x_in[s * 16 + r];
                xv[jj] = ((8 * q + jj) < remS) ? x : 0.0f;
            }
            u32x4 t;
            #pragma unroll
            for (int d = 0; d < 4; ++d) t[d] = pkh(xv[2 * d], xv[2 * d + 1]);
            ax[h] = __builtin_bit_cast(f16x8, t);
        }

        // ---- h1 (lane = slot): pos already prefetched ----
        float d0 = pi0 - pox;
        float d1 = pi1 - poy;
        float d2 = pi2 - poz;
        unsigned int hp[8];
        #pragma unroll
        for (int cp = 0; cp < 8; ++cp) {
            float a0 = celu1(fmaf(d0, w1a[2 * cp],     fmaf(d1, w1b[2 * cp],     d2 * w1c[2 * cp])));
            float a1 = celu1(fmaf(d0, w1a[2 * cp + 1], fmaf(d1, w1b[2 * cp + 1], d2 * w1c[2 * cp + 1])));
            hp[cp] = pkh(a0, a1);
        }
        *(u32x4*)(H2L + lane * 48)      = (u32x4){hp[0], hp[1], hp[2], hp[3]};
        *(u32x4*)(H2L + lane * 48 + 16) = (u32x4){hp[4], hp[5], hp[6], hp[7]};
        f16x8 af[4];
        #pragma unroll
        for (int et = 0; et < 4; ++et) {
            int abase = (q < 2) ? ((et * 16 + r) * 48 + q * 16) : 9200;
            af[et] = __builtin_bit_cast(f16x8, *(const u32x4*)(H2L + abase));
        }

        // ---- h2 = celu(h1 @ W2) via MFMA; tile write H2L[m][slot] ----
        #pragma unroll
        for (int pp = 0; pp < 2; ++pp) {
            f32x4 D[4][2];
            #pragma unroll
            for (int et = 0; et < 4; ++et)
                #pragma unroll
                for (int j = 0; j < 2; ++j)
                    D[et][j] = __builtin_amdgcn_mfma_f32_16x16x32_f16(
                        af[et], bfr[2 * pp + j], (f32x4){0.f, 0.f, 0.f, 0.f}, 0, 0, 0);
            #pragma unroll
            for (int et = 0; et < 4; ++et)
                #pragma unroll
                for (int j = 0; j < 2; ++j) {
                    int nt = 2 * pp + j;
                    float v0 = celu1(D[et][j][0]);
                    float v1 = celu1(D[et][j][1]);
                    float v2 = celu1(D[et][j][2]);
                    float v3 = celu1(D[et][j][3]);
                    *(u32x2*)(H2L + (nt * 16 + r) * 144 + et * 32 + q * 8) =
                        (u32x2){pkh(v0, v1), pkh(v2, v3)};
                }
        }

        // ---- pos prefetch for next batch (idxs_next has landed by now) ----
        float pi0n = 0.f, pi1n = 0.f, pi2n = 0.f;
        if (more) {
            pi0n = pos_in[idxs_next * 3 + 0];
            pi1n = pos_in[idxs_next * 3 + 1];
            pi2n = pos_in[idxs_next * 3 + 2];
        }

        // ---- P accumulation per half, flush to registers on transitions ----
        #pragma unroll
        for (int h = 0; h < 2; ++h) {
            int nS  = h ? nB : nA;
            int cfS = h ? cfB : cfA;
            if (rfl(nS) != cur_n) {
                float inv = cur_cf > 0 ? 1.0f / (float)cur_cf : 0.0f;
                #pragma unroll
                for (int mt = 0; mt < 4; ++mt) {
                    pkP0[2 * mt]     = pkh_rte(C[mt][0] * inv, C[mt][1] * inv);
                    pkP0[2 * mt + 1] = pkh_rte(C[mt][2] * inv, C[mt][3] * inv);
                }
                #pragma unroll
                for (int mt = 0; mt < 4; ++mt) C[mt] = (f32x4){0.f, 0.f, 0.f, 0.f};
                cur_n = nS; cur_cf = cfS;
            }
            #pragma unroll
            for (int mt = 0; mt < 4; ++mt) {
                f16x8 bb = __builtin_bit_cast(f16x8,
                    *(u32x4*)(H2L + (mt * 16 + r) * 144 + h * 64 + q * 16));
                C[mt] = __builtin_amdgcn_mfma_f32_16x16x32_f16(ax[h], bb, C[mt], 0, 0, 0);
            }
        }

        // ---- rotate pipeline registers ----
        if (more) {
            nA = nA2; cfA = cfA2; remA = remA2; ebA = ebA2;
            nB = nB2; cfB = cfB2; remB = remB2; ebB = ebB2;
            idxs = idxs_next;
            pox = pox2; poy = poy2; poz = poz2;
            pi0 = pi0n; pi1 = pi1n; pi2 = pi2n;
        }
    }

    // final flush (always the wave's second point -> slot 1)
    {
        float inv = cur_cf > 0 ? 1.0f / (float)cur_cf : 0.0f;
        #pragma unroll
        for (int mt = 0; mt < 4; ++mt) {
            pkP1[2 * mt]     = pkh_rte(C[mt][0] * inv, C[mt][1] * inv);
            pkP1[2 * mt + 1] = pkh_rte(C[mt][2] * inv, C[mt][3] * inv);
        }
    }
    #undef STEP_DESC

    // ================= fused output GEMM =================
    // A-tile: rows 0..15 = block-local points, 1024 f16 in k' order, 2048B/row,
    // 16B chunks XOR-swizzled by ((row&7)<<4). Lives in ldsraw[0..32768).
    __syncthreads();   // all waves done with H2L staging
    {
        int row0 = wv * 2;
        unsigned int base0 = (unsigned int)(row0 * 2048 + q * 512 + r * 32);
        unsigned int base1 = base0 + 2048u;
        unsigned int swz0 = (unsigned int)((row0 & 7) << 4);
        unsigned int swz1 = (unsigned int)(((row0 + 1) & 7) << 4);
        *(u32x4*)(ldsraw + ((base0)       ^ swz0)) = (u32x4){pkP0[0], pkP0[1], pkP0[2], pkP0[3]};
        *(u32x4*)(ldsraw + ((base0 + 16u) ^ swz0)) = (u32x4){pkP0[4], pkP0[5], pkP0[6], pkP0[7]};
        *(u32x4*)(ldsraw + ((base1)       ^ swz1)) = (u32x4){pkP1[0], pkP1[1], pkP1[2], pkP1[3]};
        *(u32x4*)(ldsraw + ((base1 + 16u) ^ swz1)) = (u32x4){pkP1[4], pkP1[5], pkP1[6], pkP1[7]};
    }
    __syncthreads();
    {
        // wave wv: ntile nt = wv&3 (cols nt*16..+16), k-half kh = wv>>2
        int nt = wv & 3;
        int kh = wv >> 2;
        const short8* Bp = (const short8*)W3frag + (size_t)(kh * 64 + nt) * 64 + lane;
        f32x4 Cg = (f32x4){0.f, 0.f, 0.f, 0.f};
        unsigned int abase = (unsigned int)(r * 2048 + kh * 1024 + q * 16);
        unsigned int aswz  = (unsigned int)((r & 7) << 4);
        #pragma unroll
        for (int kk = 0; kk < 16; ++kk) {
            unsigned int ad = (abase + (unsigned int)(kk * 64)) ^ aswz;
            f16x8 a  = __builtin_bit_cast(f16x8, *(const u32x4*)(ldsraw + ad));
            f16x8 bf = __builtin_bit_cast(f16x8, Bp[kk * 256]);   // frag ((kh*16+kk)*4 + nt)
            Cg = __builtin_amdgcn_mfma_f32_16x16x32_f16(a, bf, Cg, 0, 0, 0);
        }
        // split-k reduce: kh=1 waves publish partials, kh=0 waves combine.
        if (kh == 1)
            *(f32x4*)(ldsraw + 32768 + (wv - 4) * 1024 + lane * 16) = Cg;
        __syncthreads();
        if (kh == 0) {
            f32x4 Cp = *(const f32x4*)(ldsraw + 32768 + wv * 1024 + lane * 16);
            int colbase = nt * 16 + r;
            float bias = b3[colbase];
            #pragma unroll
            for (int i = 0; i < 4; ++i) {
                int prow = perm[blockIdx.x * 16 + q * 4 + i];
                out[(size_t)prow * 64 + colbase] = Cg[i] + Cp[i] + bias;
            }
        }
    }
}

extern "C" void kernel_launch(void* const* d_in, const int* in_sizes, int n_in,
                              void* d_out, int out_size, void* d_ws, size_t ws_size,
                              hipStream_t stream)
{
    const float* x_in    = (const float*)d_in[0];
    const float* pos_in  = (const float*)d_in[1];
    const float* pos_out = (const float*)d_in[2];
    const int* in_index  = (const int*)d_in[3];
    const int* out_index = (const int*)d_in[4];
    const float* W1 = (const float*)d_in[5];
    const float* W2 = (const float*)d_in[6];
    const float* W3 = (const float*)d_in[7];
    const float* b3 = (const float*)d_in[8];

    int N = in_sizes[0] / 16;    // 32768
    int E = in_sizes[3];         // 786432
    float* out = (float*)d_out;

    // workspace: seg (N+1) | W3frag (128KB) | W2f16 (4KB) | perm (N) | cnts (2)
    char* ws = (char*)d_ws;
    int* seg = (int*)ws;
    size_t off = (((size_t)(N + 1) * 4 + 255) & ~(size_t)255);
    __fp16* W3frag = (__fp16*)(ws + off);
    off += (size_t)65536 * 2;
    unsigned int* W2f16 = (unsigned int*)(ws + off);
    off += (size_t)1024 * 4;
    int* perm = (int*)(ws + off);
    off += (size_t)N * 4;
    int* cnts = (int*)(ws + off);

    setup_kernel<<<(E + 255) / 256, 256, 0, stream>>>(out_index, seg, E, N,
                                                      W3, W2, W3frag, W2f16, cnts);
    sort_kernel<<<(N + 255) / 256, 256, 0, stream>>>(seg, perm, cnts, N);
    agg_kernel<<<N / 16, 512, 0, stream>>>(x_in, pos_in, pos_out, in_index, seg,
                                           perm, W1, W2f16, W3frag, b3, out, E);
}

// Round 6
// 133.904 us; speedup vs baseline: 1.0828x; 1.0422x over previous
//
#include <hip/hip_runtime.h>
#include <hip/hip_bf16.h>

// PointConv: N=32768 points, E=786432 edges (sorted by out_index), K<=64
// product[n][c][m] = inv_n * sum_edges x_in[src][c] * celu(celu(pos_local@W1)@W2)[m]
// out[n][k] = product[n].flat(1024) @ W3[1024][64] + b3[k]
//
// R17: J=2 sequential point-pairs per wave (8 waves x 4 pts = 32 pts/block,
// 1024 blocks). Epilogue W3frag L2 traffic halves again (128MB total); A-tile
// (32 rows x 2KB = 64KB) + split-k partials (8KB) exactly reuse the dead
// 73728B staging region -> LDS/occupancy unchanged vs R16. Packed P for 4
// points kept in named u32x4 registers (static indexing, no scratch).

typedef __attribute__((ext_vector_type(8))) short short8;
typedef __attribute__((ext_vector_type(4))) float f32x4;
typedef __attribute__((ext_vector_type(2))) unsigned int u32x2;
typedef __attribute__((ext_vector_type(4))) unsigned int u32x4;
typedef __fp16 f16x2 __attribute__((ext_vector_type(2)));
typedef __fp16 f16x8 __attribute__((ext_vector_type(8)));

static __device__ __forceinline__ int rfl(int v){
    return __builtin_amdgcn_readfirstlane(v);
}
static __device__ __forceinline__ float celu1(float x){
    return x > 0.0f ? x : (__expf(x) - 1.0f);
}
static __device__ __forceinline__ unsigned int pkh(float lo, float hi){
    f16x2 t = __builtin_amdgcn_cvt_pkrtz(lo, hi);
    return __builtin_bit_cast(unsigned int, t);
}
// round-to-nearest-even f16 pack (matches previous (__fp16) casts of P)
static __device__ __forceinline__ unsigned int pkh_rte(float lo, float hi){
    unsigned short a = __builtin_bit_cast(unsigned short, (__fp16)lo);
    unsigned short b = __builtin_bit_cast(unsigned short, (__fp16)hi);
    return (unsigned int)a | ((unsigned int)b << 16);
}

// ---------------- Kernel 0: seg boundaries + W3/W2 prep (merged) -------------
// W3frag is fragment-ordered for n-tile t, K-chunk kk with the PERMUTED k':
//   k' = q*256 + r*16 + mt*4 + i   <->   k = (q*4+i)*64 + mt*16 + r
// so the agg epilogue's A-side (flush-register order) and B-side agree.
__global__ void setup_kernel(const int* __restrict__ out_index,
                             int* __restrict__ seg_start, int E, int N,
                             const float* __restrict__ W3, const float* __restrict__ W2,
                             __fp16* __restrict__ W3frag,
                             unsigned int* __restrict__ W2f16,
                             int* __restrict__ cnts)
{
    int o = blockIdx.x * blockDim.x + threadIdx.x;
    if (o == 0) { cnts[0] = 0; cnts[1] = 0; }
    if (o < E) {
        int cur = out_index[o];
        if (o == 0) {
            for (int v = 0; v <= cur; ++v) seg_start[v] = 0;
        } else {
            int prev = out_index[o - 1];
            for (int v = prev + 1; v <= cur; ++v) seg_start[v] = o;
        }
        if (o == E - 1) {
            for (int v = cur + 1; v <= N; ++v) seg_start[v] = E;
        }
    }
    if (o < 65536) {
        int j    = o & 7;
        int lane = (o >> 3) & 63;
        int t    = (o >> 9) & 3;
        int kk   = o >> 11;
        int kp = kk * 32 + (lane >> 4) * 8 + j;      // permuted k'
        int qq = kp >> 8;
        int rr = (kp >> 4) & 15;
        int mt = (kp >> 2) & 3;
        int ii = kp & 3;
        int k = (qq * 4 + ii) * 64 + mt * 16 + rr;   // true flat k = c*64 + m
        int n = t * 16 + (lane & 15);
        W3frag[o] = (__fp16)W3[k * 64 + n];
    } else if (o < 65536 + 1024) {
        int o2 = o - 65536;
        int nt   = o2 >> 8;
        int lane = (o2 >> 2) & 63;
        int d    = o2 & 3;
        int q = lane >> 4, rr = lane & 15;
        unsigned int v = 0;
        if (q < 2) {
            int k0 = q * 8 + 2 * d;
            int n = nt * 16 + rr;
            v = pkh(W2[k0 * 64 + n], W2[(k0 + 1) * 64 + n]);
        }
        W2f16[o2] = v;
    }
}

// ---------------- Kernel 0b: bucket points by step count (cheap) -------------
// cnt<=32 (1 K-step) -> slots from the front; cnt>32 -> from the back.
// Block-aggregated: ballot/popc per wave, LDS scan across 4 waves, 2 atomics
// per block. Within-bucket order arbitrary; output indexed by point id.
__global__ __launch_bounds__(256) void sort_kernel(
    const int* __restrict__ seg_start,
    int* __restrict__ perm, int* __restrict__ cnts, int N)
{
    __shared__ int wh[4], wo[4];
    __shared__ int baseH, baseL;
    int v = blockIdx.x * 256 + threadIdx.x;
    int lane = threadIdx.x & 63;
    int wv = threadIdx.x >> 6;
    int cnt = (v < N) ? (seg_start[v + 1] - seg_start[v]) : 0;
    bool heavy = (v < N) && (cnt > 32);
    unsigned long long m = __ballot(heavy);
    int hpref = __popcll(m & ((1ull << lane) - 1ull));   // heavies before me in wave
    int hcnt = __popcll(m);
    if (lane == 0) wh[wv] = hcnt;
    __syncthreads();
    if (threadIdx.x == 0) {
        int t = 0;
        #pragma unroll
        for (int i = 0; i < 4; ++i) { wo[i] = t; t += wh[i]; }
        int nval = N - blockIdx.x * 256; if (nval > 256) nval = 256;
        baseH = atomicAdd(&cnts[1], t);
        baseL = atomicAdd(&cnts[0], nval - t);
    }
    __syncthreads();
    if (v < N) {
        if (heavy) {
            perm[N - 1 - (baseH + wo[wv] + hpref)] = v;
        } else {
            int lightsBeforeWave = wv * 64 - wo[wv];
            perm[baseL + lightsBeforeWave + (lane - hpref)] = v;
        }
    }
}

// ---------------- Kernel 1: edge aggregation + fused output GEMM -------------
// Wave wv (0..7) processes pairs (blockIdx*16 + wv*2 + j), j=0,1; block owns
// 32 consecutive sorted points.
__global__ __launch_bounds__(512) void agg_kernel(
    const float* __restrict__ x_in, const float* __restrict__ pos_in,
    const float* __restrict__ pos_out, const int* __restrict__ in_index,
    const int* __restrict__ seg_start, const int* __restrict__ perm,
    const float* __restrict__ W1,
    const unsigned int* __restrict__ W2f16, const __fp16* __restrict__ W3frag,
    const float* __restrict__ b3, float* __restrict__ out, int E)
{
    __shared__ __align__(16) unsigned char ldsraw[8 * 9216];
    int lane = threadIdx.x & 63;
    int wv = threadIdx.x >> 6;                 // 0..7
    unsigned char* H2L = ldsraw + wv * 9216;   // staging 0..3071; tile rows m*144
    int r = lane & 15;
    int q = lane >> 4;
    int l31 = lane & 31;
    bool hihalf = lane >= 32;
    int vq = 32 * q;                           // byte-addr component for bpermute

    // zero block for padded-K A-frag lanes (bytes 9200..9215 never written)
    if (lane == 0) *(u32x4*)(H2L + 9200) = (u32x4){0u, 0u, 0u, 0u};

    // W2 B-frags (constant)
    f16x8 bfr[4];
    #pragma unroll
    for (int nt = 0; nt < 4; ++nt)
        bfr[nt] = __builtin_bit_cast(f16x8, *((const u32x4*)W2f16 + nt * 64 + lane));

    // W1 columns (uniform -> SGPRs)
    float w1a[16], w1b[16], w1c[16];
    #pragma unroll
    for (int c = 0; c < 16; ++c) { w1a[c] = W1[c]; w1b[c] = W1[16 + c]; w1c[c] = W1[32 + c]; }

    // packed f16 products for the wave's 4 points (named regs, static access)
    u32x4 pA0l, pA0h, pA1l, pA1h, pB0l, pB0h, pB1l, pB1h;

    // ---- full per-pair pipeline (identical to R16 main loop) ----
    auto run_pair = [&](int pj, u32x4& P0l, u32x4& P0h, u32x4& P1l, u32x4& P1h) {
        int pw = blockIdx.x * 16 + wv * 2 + pj;
        int pid[2], sg[2], cf[2], cc[2], p[3];
        pid[0] = rfl(perm[pw * 2]);
        pid[1] = rfl(perm[pw * 2 + 1]);
        p[0] = 0;
        #pragma unroll
        for (int i = 0; i < 2; ++i) {
            sg[i] = rfl(seg_start[pid[i]]);
            int se = rfl(seg_start[pid[i] + 1]);
            cf[i] = se - sg[i];
            cc[i] = cf[i] > 64 ? 64 : cf[i];
            p[i + 1] = p[i] + (cc[i] > 32 ? 2 : 1);
        }
        int ns = p[2];                         // total 32-slot steps, 2..4

        #define STEP_DESC(t, nS, cfS, remS, ebS)                         \
            {                                                            \
                int i_ = 0, pi_ = 0;                                     \
                if ((t) >= p[1]) { i_ = 1; pi_ = p[1]; }                 \
                int cf_ = cf[0], cc_ = cc[0], sg_ = sg[0], id_ = pid[0]; \
                if (i_ >= 1) { cf_ = cf[1]; cc_ = cc[1]; sg_ = sg[1]; id_ = pid[1]; } \
                int kb_ = ((t) - pi_) * 32;                              \
                (nS) = id_; (cfS) = cf_;                                 \
                (remS) = cc_ - kb_; (ebS) = sg_ + kb_;                   \
            }

        f32x4 C[4];
        #pragma unroll
        for (int mt = 0; mt < 4; ++mt) C[mt] = (f32x4){0.f, 0.f, 0.f, 0.f};
        int cur_n = pid[0];
        int cur_cf = cf[0];

        // prologue: batch 0 descriptors + idx + pos prefetch
        int nA, cfA, remA, ebA, nB, cfB, remB, ebB;
        STEP_DESC(0, nA, cfA, remA, ebA)
        STEP_DESC(1, nB, cfB, remB, ebB)
        int nH = hihalf ? nB : nA;
        int ebH = hihalf ? ebB : ebA;
        int idx0 = ebH + l31; idx0 = idx0 < E ? idx0 : E - 1;
        int idxs = in_index[idx0];             // lane l -> src of slot l
        float pox = pos_out[nH * 3 + 0];
        float poy = pos_out[nH * 3 + 1];
        float poz = pos_out[nH * 3 + 2];
        float pi0 = pos_in[idxs * 3 + 0];
        float pi1 = pos_in[idxs * 3 + 1];
        float pi2 = pos_in[idxs * 3 + 2];

        #pragma unroll 1
        for (int b = 0; b < 2; ++b) {
            if (2 * b >= ns) break;
            bool more = (2 * b + 2) < ns;      // wave-uniform

            // prefetch next batch: descriptors + idx vector (only if real)
            int nA2 = 0, cfA2 = 0, remA2 = 0, ebA2 = 0;
            int nB2 = 0, cfB2 = 0, remB2 = 0, ebB2 = 0;
            int idxs_next = 0;
            float pox2 = 0.f, poy2 = 0.f, poz2 = 0.f;
            if (more) {
                STEP_DESC(2 * b + 2, nA2, cfA2, remA2, ebA2)
                STEP_DESC(2 * b + 3, nB2, cfB2, remB2, ebB2)
                int nH2 = hihalf ? nB2 : nA2;
                int ebH2 = hihalf ? ebB2 : ebA2;
                int idx2 = ebH2 + l31; idx2 = idx2 < E ? idx2 : E - 1;
                idxs_next = in_index[idx2];
                pox2 = pos_out[nH2 * 3 + 0];
                poy2 = pos_out[nH2 * 3 + 1];
                poz2 = pos_out[nH2 * 3 + 2];
            }

            // x A-frags: src via bpermute of idxs (loaded last iter)
            f16x8 ax[2];
            #pragma unroll
            for (int h = 0; h < 2; ++h) {
                int remS = h ? remB : remA;
                float xv[8];
                #pragma unroll
                for (int jj = 0; jj < 8; ++jj) {
                    // slot = 32h + 8q + jj; bpermute byte addr = 4*slot
                    int s = __builtin_amdgcn_ds_bpermute(128 * h + vq + 4 * jj, idxs);
                    float x = x_in[s * 16 + r];
                    xv[jj] = ((8 * q + jj) < remS) ? x : 0.0f;
                }
                u32x4 t;
                #pragma unroll
                for (int d = 0; d < 4; ++d) t[d] = pkh(xv[2 * d], xv[2 * d + 1]);
                ax[h] = __builtin_bit_cast(f16x8, t);
            }

            // h1 (lane = slot): pos already prefetched
            float d0 = pi0 - pox;
            float d1 = pi1 - poy;
            float d2 = pi2 - poz;
            unsigned int hp[8];
            #pragma unroll
            for (int cp = 0; cp < 8; ++cp) {
                float a0 = celu1(fmaf(d0, w1a[2 * cp],     fmaf(d1, w1b[2 * cp],     d2 * w1c[2 * cp])));
                float a1 = celu1(fmaf(d0, w1a[2 * cp + 1], fmaf(d1, w1b[2 * cp + 1], d2 * w1c[2 * cp + 1])));
                hp[cp] = pkh(a0, a1);
            }
            *(u32x4*)(H2L + lane * 48)      = (u32x4){hp[0], hp[1], hp[2], hp[3]};
            *(u32x4*)(H2L + lane * 48 + 16) = (u32x4){hp[4], hp[5], hp[6], hp[7]};
            f16x8 af[4];
            #pragma unroll
            for (int et = 0; et < 4; ++et) {
                int abase = (q < 2) ? ((et * 16 + r) * 48 + q * 16) : 9200;
                af[et] = __builtin_bit_cast(f16x8, *(const u32x4*)(H2L + abase));
            }

            // h2 = celu(h1 @ W2) via MFMA; tile write H2L[m][slot]
            #pragma unroll
            for (int pp = 0; pp < 2; ++pp) {
                f32x4 D[4][2];
                #pragma unroll
                for (int et = 0; et < 4; ++et)
                    #pragma unroll
                    for (int j = 0; j < 2; ++j)
                        D[et][j] = __builtin_amdgcn_mfma_f32_16x16x32_f16(
                            af[et], bfr[2 * pp + j], (f32x4){0.f, 0.f, 0.f, 0.f}, 0, 0, 0);
                #pragma unroll
                for (int et = 0; et < 4; ++et)
                    #pragma unroll
                    for (int j = 0; j < 2; ++j) {
                        int nt = 2 * pp + j;
                        float v0 = celu1(D[et][j][0]);
                        float v1 = celu1(D[et][j][1]);
                        float v2 = celu1(D[et][j][2]);
                        float v3 = celu1(D[et][j][3]);
                        *(u32x2*)(H2L + (nt * 16 + r) * 144 + et * 32 + q * 8) =
                            (u32x2){pkh(v0, v1), pkh(v2, v3)};
                    }
            }

            // pos prefetch for next batch (idxs_next has landed by now)
            float pi0n = 0.f, pi1n = 0.f, pi2n = 0.f;
            if (more) {
                pi0n = pos_in[idxs_next * 3 + 0];
                pi1n = pos_in[idxs_next * 3 + 1];
                pi2n = pos_in[idxs_next * 3 + 2];
            }

            // P accumulation per half, flush to registers on transitions
            #pragma unroll
            for (int h = 0; h < 2; ++h) {
                int nS  = h ? nB : nA;
                int cfS = h ? cfB : cfA;
                if (rfl(nS) != cur_n) {
                    float inv = cur_cf > 0 ? 1.0f / (float)cur_cf : 0.0f;
                    P0l = (u32x4){pkh_rte(C[0][0] * inv, C[0][1] * inv),
                                  pkh_rte(C[0][2] * inv, C[0][3] * inv),
                                  pkh_rte(C[1][0] * inv, C[1][1] * inv),
                                  pkh_rte(C[1][2] * inv, C[1][3] * inv)};
                    P0h = (u32x4){pkh_rte(C[2][0] * inv, C[2][1] * inv),
                                  pkh_rte(C[2][2] * inv, C[2][3] * inv),
                                  pkh_rte(C[3][0] * inv, C[3][1] * inv),
                                  pkh_rte(C[3][2] * inv, C[3][3] * inv)};
                    #pragma unroll
                    for (int mt = 0; mt < 4; ++mt) C[mt] = (f32x4){0.f, 0.f, 0.f, 0.f};
                    cur_n = nS; cur_cf = cfS;
                }
                #pragma unroll
                for (int mt = 0; mt < 4; ++mt) {
                    f16x8 bb = __builtin_bit_cast(f16x8,
                        *(u32x4*)(H2L + (mt * 16 + r) * 144 + h * 64 + q * 16));
                    C[mt] = __builtin_amdgcn_mfma_f32_16x16x32_f16(ax[h], bb, C[mt], 0, 0, 0);
                }
            }

            // rotate pipeline registers
            if (more) {
                nA = nA2; cfA = cfA2; remA = remA2; ebA = ebA2;
                nB = nB2; cfB = cfB2; remB = remB2; ebB = ebB2;
                idxs = idxs_next;
                pox = pox2; poy = poy2; poz = poz2;
                pi0 = pi0n; pi1 = pi1n; pi2 = pi2n;
            }
        }

        // final flush (always the pair's second point -> slot 1)
        {
            float inv = cur_cf > 0 ? 1.0f / (float)cur_cf : 0.0f;
            P1l = (u32x4){pkh_rte(C[0][0] * inv, C[0][1] * inv),
                          pkh_rte(C[0][2] * inv, C[0][3] * inv),
                          pkh_rte(C[1][0] * inv, C[1][1] * inv),
                          pkh_rte(C[1][2] * inv, C[1][3] * inv)};
            P1h = (u32x4){pkh_rte(C[2][0] * inv, C[2][1] * inv),
                          pkh_rte(C[2][2] * inv, C[2][3] * inv),
                          pkh_rte(C[3][0] * inv, C[3][1] * inv),
                          pkh_rte(C[3][2] * inv, C[3][3] * inv)};
        }
        #undef STEP_DESC
    };

    run_pair(0, pA0l, pA0h, pA1l, pA1h);
    run_pair(1, pB0l, pB0h, pB1l, pB1h);

    // ================= fused output GEMM (32-point M-tile) =================
    // A-tile: rows 0..31 = block-local points, 1024 f16 in k' order, 2048B/row,
    // 16B chunks XOR-swizzled by ((row&7)<<4). Overlays the dead staging
    // region; split-k partials live at 65536..73727.
    __syncthreads();   // all waves done with H2L staging
    {
        auto storeP = [&](int row, u32x4 lo, u32x4 hi) {
            unsigned int base = (unsigned int)(row * 2048 + q * 512 + r * 32);
            unsigned int swz = (unsigned int)((row & 7) << 4);
            *(u32x4*)(ldsraw + (base ^ swz)) = lo;
            *(u32x4*)(ldsraw + ((base + 16u) ^ swz)) = hi;
        };
        int row0 = wv * 4;
        storeP(row0 + 0, pA0l, pA0h);
        storeP(row0 + 1, pA1l, pA1h);
        storeP(row0 + 2, pB0l, pB0h);
        storeP(row0 + 3, pB1l, pB1h);
    }
    __syncthreads();
    {
        // wave wv: ntile nt = wv&3 (cols nt*16..+16), k-half kh = wv>>2.
        // 2 row-tiles per wave; each B-frag loaded once, used twice.
        int nt = wv & 3;
        int kh = wv >> 2;
        const short8* Bp = (const short8*)W3frag + (size_t)(kh * 64 + nt) * 64 + lane;
        f32x4 Cg0 = (f32x4){0.f, 0.f, 0.f, 0.f};
        f32x4 Cg1 = (f32x4){0.f, 0.f, 0.f, 0.f};
        unsigned int aswz = (unsigned int)((r & 7) << 4);
        unsigned int ab0 = (unsigned int)(r * 2048 + kh * 1024 + q * 16);
        unsigned int ab1 = ab0 + 16u * 2048u;
        #pragma unroll
        for (int kk = 0; kk < 16; ++kk) {
            f16x8 bf = __builtin_bit_cast(f16x8, Bp[kk * 256]);   // frag ((kh*16+kk)*4 + nt)
            f16x8 a0 = __builtin_bit_cast(f16x8,
                *(const u32x4*)(ldsraw + ((ab0 + (unsigned int)(kk * 64)) ^ aswz)));
            f16x8 a1 = __builtin_bit_cast(f16x8,
                *(const u32x4*)(ldsraw + ((ab1 + (unsigned int)(kk * 64)) ^ aswz)));
            Cg0 = __builtin_amdgcn_mfma_f32_16x16x32_f16(a0, bf, Cg0, 0, 0, 0);
            Cg1 = __builtin_amdgcn_mfma_f32_16x16x32_f16(a1, bf, Cg1, 0, 0, 0);
        }
        // split-k reduce: kh=1 waves publish partials, kh=0 waves combine.
        if (kh == 1) {
            *(f32x4*)(ldsraw + 65536 + (wv - 4) * 2048 + lane * 16) = Cg0;
            *(f32x4*)(ldsraw + 65536 + (wv - 4) * 2048 + 1024 + lane * 16) = Cg1;
        }
        __syncthreads();
        if (kh == 0) {
            f32x4 Cp0 = *(const f32x4*)(ldsraw + 65536 + wv * 2048 + lane * 16);
            f32x4 Cp1 = *(const f32x4*)(ldsraw + 65536 + wv * 2048 + 1024 + lane * 16);
            int colbase = nt * 16 + r;
            float bias = b3[colbase];
            #pragma unroll
            for (int i = 0; i < 4; ++i) {
                int prow0 = perm[blockIdx.x * 32 + q * 4 + i];
                out[(size_t)prow0 * 64 + colbase] = Cg0[i] + Cp0[i] + bias;
            }
            #pragma unroll
            for (int i = 0; i < 4; ++i) {
                int prow1 = perm[blockIdx.x * 32 + 16 + q * 4 + i];
                out[(size_t)prow1 * 64 + colbase] = Cg1[i] + Cp1[i] + bias;
            }
        }
    }
}

extern "C" void kernel_launch(void* const* d_in, const int* in_sizes, int n_in,
                              void* d_out, int out_size, void* d_ws, size_t ws_size,
                              hipStream_t stream)
{
    const float* x_in    = (const float*)d_in[0];
    const float* pos_in  = (const float*)d_in[1];
    const float* pos_out = (const float*)d_in[2];
    const int* in_index  = (const int*)d_in[3];
    const int* out_index = (const int*)d_in[4];
    const float* W1 = (const float*)d_in[5];
    const float* W2 = (const float*)d_in[6];
    const float* W3 = (const float*)d_in[7];
    const float* b3 = (const float*)d_in[8];

    int N = in_sizes[0] / 16;    // 32768
    int E = in_sizes[3];         // 786432
    float* out = (float*)d_out;

    // workspace: seg (N+1) | W3frag (128KB) | W2f16 (4KB) | perm (N) | cnts (2)
    char* ws = (char*)d_ws;
    int* seg = (int*)ws;
    size_t off = (((size_t)(N + 1) * 4 + 255) & ~(size_t)255);
    __fp16* W3frag = (__fp16*)(ws + off);
    off += (size_t)65536 * 2;
    unsigned int* W2f16 = (unsigned int*)(ws + off);
    off += (size_t)1024 * 4;
    int* perm = (int*)(ws + off);
    off += (size_t)N * 4;
    int* cnts = (int*)(ws + off);

    setup_kernel<<<(E + 255) / 256, 256, 0, stream>>>(out_index, seg, E, N,
                                                      W3, W2, W3frag, W2f16, cnts);
    sort_kernel<<<(N + 255) / 256, 256, 0, stream>>>(seg, perm, cnts, N);
    agg_kernel<<<N / 32, 512, 0, stream>>>(x_in, pos_in, pos_out, in_index, seg,
                                           perm, W1, W2f16, W3frag, b3, out, E);
}